// Round 3
// baseline (527.625 us; speedup 1.0000x reference)
//
#include <hip/hip_runtime.h>
#include <hip/hip_bf16.h>

#define BB 8
#define CC 64
#define NN 4096
#define KK 20
#define OO 64
#define FMAXV 3.402823466e38f

typedef __attribute__((ext_vector_type(8))) short short8;   // 8 bf16 = 4 VGPRs (MFMA A/B frag)
typedef __attribute__((ext_vector_type(4))) float f32x4;    // MFMA C/D frag

// ---------------------------------------------------------------------------
// Kernel PREP (verified r7): transpose x (B,C,N)->xt/xb (B,N,C), sq, u/v GEMV.
// ---------------------------------------------------------------------------
__global__ __launch_bounds__(256) void kprep(const float* __restrict__ x,
                                             const float* __restrict__ W,
                                             const float* __restrict__ bias,
                                             float* __restrict__ xt,
                                             unsigned short* __restrict__ xb,
                                             float* __restrict__ sq,
                                             float* __restrict__ u,
                                             float* __restrict__ v) {
  __shared__ float tile[64][65];       // [c][n]
  const int b = blockIdx.y, n0 = blockIdx.x * 64;
  const int lane = threadIdx.x & 63, grp = threadIdx.x >> 6;
  #pragma unroll
  for (int j = 0; j < 16; ++j) {
    int c = grp + j * 4;
    tile[c][lane] = x[((size_t)b * CC + c) * NN + n0 + lane];
  }
  float w2r[64], wdr[64];
  const float4* W4 = (const float4*)W;
  #pragma unroll
  for (int c4 = 0; c4 < 16; ++c4) {
    float4 q1 = W4[lane * 32 + c4];       // W1 part
    float4 q2 = W4[lane * 32 + 16 + c4];  // W2 part
    w2r[c4*4]=q2.x; w2r[c4*4+1]=q2.y; w2r[c4*4+2]=q2.z; w2r[c4*4+3]=q2.w;
    wdr[c4*4]=q1.x-q2.x; wdr[c4*4+1]=q1.y-q2.y; wdr[c4*4+2]=q1.z-q2.z; wdr[c4*4+3]=q1.w-q2.w;
  }
  const float bo = bias[lane];
  __syncthreads();
  #pragma unroll
  for (int j = 0; j < 16; ++j) {
    int n = grp + j * 4;
    float vv = tile[lane][n];
    size_t off = ((size_t)b * NN + n0 + n) * CC + lane;
    xt[off] = vv;
    unsigned int uu = __builtin_bit_cast(unsigned int, vv);
    xb[off] = (unsigned short)((uu + 0x7FFFu + ((uu >> 16) & 1u)) >> 16);  // RNE bf16
  }
  if (threadIdx.x < 64) {
    float s = 0.f;
    #pragma unroll
    for (int c = 0; c < 64; ++c) { float vv = tile[c][lane]; s += vv * vv; }
    sq[(size_t)b * NN + n0 + lane] = s;
  }
  for (int j = 0; j < 16; ++j) {
    int nl = grp * 16 + j;
    float du = 0.f, dv = 0.f;
    #pragma unroll
    for (int c = 0; c < 64; ++c) {
      float xv = tile[c][nl];             // broadcast read
      du += w2r[c] * xv;
      dv += wdr[c] * xv;
    }
    size_t off = ((size_t)b * NN + n0 + nl) * OO + lane;
    u[off] = du;
    v[off] = dv + bo;
  }
}

// ---------------------------------------------------------------------------
// helpers (verified rounds 3-8)
// ---------------------------------------------------------------------------
__device__ __forceinline__ int lanes_below(unsigned long long m) {
  unsigned lo = (unsigned)m, hi = (unsigned)(m >> 32);
  int c = __builtin_amdgcn_mbcnt_lo(lo, 0);
  return (int)__builtin_amdgcn_mbcnt_hi(hi, (unsigned)c);
}

// monotone float->uint, truncate to 20 bits, pack 12-bit global col idx
__device__ __forceinline__ unsigned packkey(float d, int m) {
  unsigned u = __builtin_bit_cast(unsigned, d);
  u ^= ((int)u < 0) ? 0xFFFFFFFFu : 0x80000000u;
  return (u & 0xFFFFF000u) | (unsigned)m;
}

// loose inverse: float threshold >= every d whose packkey < t (superset filter)
__device__ __forceinline__ float unpackkey(unsigned t) {
  unsigned u = t | 0xFFFu;
  u = (u & 0x80000000u) ? (u ^ 0x80000000u) : ~u;
  return __builtin_bit_cast(float, u);
}

// full 64-element bitonic sort (ascending), 1 element per lane, 21 stages
__device__ __forceinline__ unsigned bitonic64(unsigned v, int lane) {
  #pragma unroll
  for (int k = 2; k <= 64; k <<= 1) {
    #pragma unroll
    for (int j = k >> 1; j >= 1; j >>= 1) {
      unsigned o = (unsigned)__shfl_xor((int)v, j);
      bool up    = ((lane & k) == 0);
      bool lower = ((lane & j) == 0);
      unsigned mn = (v < o) ? v : o;
      unsigned mx = (v < o) ? o : v;
      v = (up == lower) ? mn : mx;
    }
  }
  return v;
}

// bitonic MERGE (6 stages): input ascending in lanes 0-31, descending in 32-63
// -> output fully sorted ascending across 64 lanes.
__device__ __forceinline__ unsigned merge6(unsigned v, int lane) {
  #pragma unroll
  for (int j = 32; j >= 1; j >>= 1) {
    unsigned o = (unsigned)__shfl_xor((int)v, j);
    unsigned mn = (v < o) ? v : o;
    unsigned mx = (v < o) ? o : v;
    v = ((lane & j) == 0) ? mn : mx;
  }
  return v;
}

// ---------------------------------------------------------------------------
// Kernel KNN8 (r9): QUARTER-column split for occupancy. Each wave: 16 rows x
// 1024 cols (16 tiles). Ring is 48 entries with wrapped o4/w4/r4 pointers
// (merge-check per ct bounds outstanding to 31+16=47). LDS = 20480 B/block ->
// 8 blocks/CU -> 32 waves/CU, entire 2048-block grid co-resident (no tail).
// Self-match included (strict exact min, dropped in kpost).
// Output: kcand[b][quarter][row][32] SORTED ascending packed keys.
// ---------------------------------------------------------------------------
__global__ __launch_bounds__(256, 8) void kknn8(const unsigned short* __restrict__ xb,
                                                const float* __restrict__ sq,
                                                unsigned* __restrict__ kcand) {
  __shared__ unsigned slist[4][16][32];   //  8 KB: per-wave per-row sorted top-32
  __shared__ unsigned sbuf[4][16][48];    // 12 KB: per-wave per-row ring (outstanding <= 47)
  const int lane = threadIdx.x & 63, w = threadIdx.x >> 6;
  const int wid = blockIdx.x * 4 + w;            // 0..8191
  const int b = wid >> 10;
  const int quarter = (wid >> 8) & 3;
  const int n0g = (wid & 255) * 16;              // global row base
  const int ch0 = quarter * (NN / 4);            // global col base
  const int l15 = lane & 15, q = lane >> 4;
  const unsigned long long qmask = 0xFFFFull << (q * 16);

  const unsigned short* xbB = xb + (size_t)b * NN * CC;
  const float* sqB = sq + (size_t)b * NN;

  // init slist sentinels (per wave)
  #pragma unroll
  for (int i = 0; i < 8; ++i) {
    int idx = i * 64 + lane;
    slist[w][idx >> 5][idx & 31] = 0xFFFFFFFFu;
  }

  // A frags: rows n0g + l15, k = ks*32 + q*8
  short8 afr[2];
  #pragma unroll
  for (int ks = 0; ks < 2; ++ks)
    afr[ks] = __builtin_bit_cast(short8, *(const int4*)(xbB + (size_t)(n0g + l15) * CC + ks * 32 + q * 8));

  // per-lane state: slot j tracks row q*4+j
  float tauf4[4];
  int o4[4], w4[4], r4[4];                // outstanding, wrapped write ptr, wrapped read ptr
  #pragma unroll
  for (int j = 0; j < 4; ++j) { tauf4[j] = FMAXV; o4[j] = 0; w4[j] = 0; r4[j] = 0; }

  for (int t = 0; t < 16; ++t) {
    const int cb = ch0 + t * 64;
    short8 bfr[4][2];
    float sv[4];
    #pragma unroll
    for (int ct = 0; ct < 4; ++ct) {
      #pragma unroll
      for (int ks = 0; ks < 2; ++ks)
        bfr[ct][ks] = __builtin_bit_cast(short8,
            *(const int4*)(xbB + (size_t)(cb + ct * 16 + l15) * CC + ks * 32 + q * 8));
      sv[ct] = sqB[cb + ct * 16 + l15];
    }
    f32x4 acc[4];
    #pragma unroll
    for (int ct = 0; ct < 4; ++ct) {
      acc[ct] = (f32x4){0.f, 0.f, 0.f, 0.f};
      acc[ct] = __builtin_amdgcn_mfma_f32_16x16x32_bf16(afr[0], bfr[ct][0], acc[ct], 0, 0, 0);
      acc[ct] = __builtin_amdgcn_mfma_f32_16x16x32_bf16(afr[1], bfr[ct][1], acc[ct], 0, 0, 0);
    }

    #pragma unroll
    for (int j = 0; j < 4; ++j) {
      float dj[4];
      bool  pj[4];
      #pragma unroll
      for (int ct = 0; ct < 4; ++ct) {
        dj[ct] = sv[ct] - 2.f * acc[ct][j];
        pj[ct] = dj[ct] <= tauf4[j];
      }
      unsigned long long bl0 = __ballot(pj[0]);
      unsigned long long bl1 = __ballot(pj[1]);
      unsigned long long bl2 = __ballot(pj[2]);
      unsigned long long bl3 = __ballot(pj[3]);
      if (!(bl0 | bl1 | bl2 | bl3)) continue;

      const int rowl = q * 4 + j;
      #pragma unroll
      for (int ct = 0; ct < 4; ++ct) {
        unsigned long long blc = (ct == 0) ? bl0 : (ct == 1) ? bl1 : (ct == 2) ? bl2 : bl3;
        unsigned long long bq = blc & qmask;
        int pos = lanes_below(bq);
        int qc  = __popcll(bq);
        if (pj[ct]) {
          int idx = w4[j] + pos; if (idx >= 48) idx -= 48;
          sbuf[w][rowl][idx] = packkey(dj[ct], cb + ct * 16 + l15);
        }
        w4[j] += qc; if (w4[j] >= 48) w4[j] -= 48;
        o4[j] += qc;

        // merge-check per ct: outstanding <= 31+16 = 47 fits ring 48;
        // one merge restores the <=31 invariant.
        unsigned long long mb = __ballot(o4[j] >= 32);
        while (mb) {
          int src = __ffsll(mb) - 1;
          int qm = src >> 4;
          int rowm = qm * 4 + j;
          int rsrc = __shfl(r4[j], src);
          int ridx = rsrc + (lane - 32); if (ridx >= 48) ridx -= 48;
          unsigned v = (lane < 32) ? slist[w][rowm][lane]
                                   : sbuf[w][rowm][ridx];
          v = bitonic64(v, lane);
          if (lane < 32) slist[w][rowm][lane] = v;
          unsigned tn = (unsigned)__shfl((int)v, 31);
          if (q == qm) {
            tauf4[j] = unpackkey(tn);
            r4[j] += 32; if (r4[j] >= 48) r4[j] -= 48;
            o4[j] -= 32;
          }
          mb &= ~(0xFFFFull << (qm * 16));
        }
      }
    }
  }

  // flush leftovers (< 32 outstanding per row)
  #pragma unroll
  for (int j = 0; j < 4; ++j) {
    unsigned long long mb = __ballot(o4[j] > 0);
    while (mb) {
      int src = __ffsll(mb) - 1;
      int qm = src >> 4;
      int rowm = qm * 4 + j;
      int rsrc = __shfl(r4[j], src);
      int rem  = __shfl(o4[j], src);
      int ridx = rsrc + (lane - 32); if (ridx >= 48) ridx -= 48;
      unsigned v = (lane < 32) ? slist[w][rowm][lane]
                 : ((lane - 32) < rem ? sbuf[w][rowm][ridx] : 0xFFFFFFFFu);
      v = bitonic64(v, lane);
      if (lane < 32) slist[w][rowm][lane] = v;
      if (q == qm) o4[j] = 0;
      mb &= ~(0xFFFFull << (qm * 16));
    }
  }

  // write out sorted top-32 per row (coalesced)
  unsigned* kc = kcand + (((size_t)b * 4 + quarter) * NN + n0g) * 32;
  #pragma unroll
  for (int i = 0; i < 8; ++i) {
    int idx = i * 64 + lane;
    kc[idx] = slist[w][idx >> 5][idx & 31];
  }
}

// ---------------------------------------------------------------------------
// preselect (r9): union 4 SORTED quarter top-32 lists of one row via three
// 6-stage bitonic merges -> approx-top-32 in lanes 0-31 (ascending).
// ---------------------------------------------------------------------------
__device__ __forceinline__ unsigned preselect(const unsigned* __restrict__ kcB,
                                              int row, int lane) {
  const int li = (lane < 32) ? lane : (63 - lane);   // upper lanes load reversed
  unsigned v01 = (lane < 32) ? kcB[((size_t)0 * NN + row) * 32 + li]
                             : kcB[((size_t)1 * NN + row) * 32 + li];
  v01 = merge6(v01, lane);                           // sorted 64; low32 = A∪B top-32
  unsigned v23 = (lane < 32) ? kcB[((size_t)2 * NN + row) * 32 + li]
                             : kcB[((size_t)3 * NN + row) * 32 + li];
  v23 = merge6(v23, lane);                           // sorted 64; low32 = C∪D top-32
  unsigned sw = (unsigned)__shfl_xor((int)v23, 63);  // reverse into upper lanes
  unsigned vm = (lane < 32) ? v01 : sw;              // asc low / desc high = bitonic
  vm = merge6(vm, lane);                             // sorted 64; low32 = row top-32
  return vm;
}

// ---------------------------------------------------------------------------
// Kernel POST (r9): per row-pair, preselect approx-top-32 from the 4 quarter
// lists -> exact f32 refine (xt) -> sorted; rank 0 is ALWAYS self (exact
// strict min), neighbors are ranks 1..20. Gather u for stats into replicated
// gS; umax/umin.
// ---------------------------------------------------------------------------
__global__ __launch_bounds__(256) void kpost(const unsigned* __restrict__ kcand,
                                             const float* __restrict__ xt,
                                             const float* __restrict__ sq,
                                             const float* __restrict__ u,
                                             const float* __restrict__ v,
                                             float* __restrict__ umax,
                                             float* __restrict__ umin,
                                             float* __restrict__ gS) {
  const int lane = threadIdx.x & 63, w = threadIdx.x >> 6;
  const int gw = blockIdx.x * 4 + w;
  const int hl = lane & 31;
  float s1 = 0.f, s2 = 0.f;

  for (int it = 0; it < 2; ++it) {
    const int rbase = gw * 4 + it * 2;          // global row index (b*N+n), even
    const int b = rbase >> 12;
    const int n = rbase & (NN - 1);

    const unsigned* kcB = kcand + (size_t)b * 4 * NN * 32;
    unsigned keyN  = preselect(kcB, n,     lane);   // lanes 0-31: row n top-32
    unsigned keyN1 = preselect(kcB, n + 1, lane);   // lanes 0-31: row n+1 top-32
    unsigned kx = (unsigned)__shfl_xor((int)keyN1, 32);
    unsigned key = (lane < 32) ? keyN : kx;     // lanes 0-31: row n; 32-63: row n+1
    int m = (int)(key & 0xFFFu);
    const int rowg = n + ((lane >= 32) ? 1 : 0);

    // exact f32 key
    const float* xtB = xt + (size_t)b * NN * CC;
    const float* sqB = sq + (size_t)b * NN;
    const float4* pr = (const float4*)(xtB + (size_t)rowg * CC);
    const float4* pm = (const float4*)(xtB + (size_t)m * CC);
    float t0 = 0.f, t1 = 0.f, t2 = 0.f, t3 = 0.f;
    #pragma unroll
    for (int i = 0; i < 16; ++i) {
      float4 a = pr[i], c = pm[i];
      t0 += a.x * c.x; t1 += a.y * c.y; t2 += a.z * c.z; t3 += a.w * c.w;
    }
    float ev = sqB[m] - 2.f * ((t0 + t1) + (t2 + t3));

    // bitonic sort 32 (ev, m) pairs ascending within each 32-lane half
    #pragma unroll
    for (int k = 2; k <= 32; k <<= 1) {
      #pragma unroll
      for (int jj = k >> 1; jj >= 1; jj >>= 1) {
        float e2 = __shfl_xor(ev, jj);
        int   m2 = __shfl_xor(m, jj);
        bool up    = ((hl & k) == 0);
        bool lower = ((hl & jj) == 0);
        bool less  = (e2 < ev) || (e2 == ev && m2 < m);
        bool take  = (up == lower) ? less : !less;
        if (take) { ev = e2; m = m2; }
      }
    }

    // stats gather: lane = channel; rows n, n+1. Rank 0 is self -> skip it.
    const float* uB = u + (size_t)b * NN * OO;
    #pragma unroll
    for (int rr = 0; rr < 2; ++rr) {
      const int rown = n + rr;
      float vv = v[((size_t)b * NN + rown) * OO + lane];
      float mx = -FMAXV, mn = FMAXV;
      #pragma unroll
      for (int k = 0; k < KK; ++k) {
        int id = __shfl(m, rr * 32 + 1 + k);
        float uu = uB[(size_t)id * OO + lane];
        float y = vv + uu;
        s1 += y; s2 += y * y;
        mx = fmaxf(mx, uu); mn = fminf(mn, uu);
      }
      umax[((size_t)b * NN + rown) * OO + lane] = mx;
      umin[((size_t)b * NN + rown) * OO + lane] = mn;
    }
  }

  __shared__ float r1[4][64], r2[4][64];
  r1[w][lane] = s1; r2[w][lane] = s2;
  __syncthreads();
  if (w == 0) {
    float a = r1[0][lane] + r1[1][lane] + r1[2][lane] + r1[3][lane];
    float c = r2[0][lane] + r2[1][lane] + r2[2][lane] + r2[3][lane];
    float* g = gS + (blockIdx.x & 7) * 128;     // 8 replicas vs atomic serialization
    atomicAdd(&g[lane], a);
    atomicAdd(&g[64 + lane], c);
  }
}

// ---------------------------------------------------------------------------
// Kernel O (verified r7): normalize, affine, relu, max over k, transposed store
// ---------------------------------------------------------------------------
__global__ __launch_bounds__(256) void kout(const float* __restrict__ v,
                                            const float* __restrict__ umax,
                                            const float* __restrict__ umin,
                                            const float* __restrict__ gS,
                                            const float* __restrict__ gamma,
                                            const float* __restrict__ beta,
                                            float* __restrict__ out) {
  __shared__ float sA[64], sB[64];
  __shared__ float zt[64][65];
  const int b = blockIdx.y, n0 = blockIdx.x * 64;
  const int lane = threadIdx.x & 63, w = threadIdx.x >> 6;
  if (threadIdx.x < 64) {
    float s1 = 0.f, s2 = 0.f;
    #pragma unroll
    for (int rsub = 0; rsub < 8; ++rsub) {
      s1 += gS[rsub * 128 + lane];
      s2 += gS[rsub * 128 + 64 + lane];
    }
    const float cnt = (float)BB * NN * KK;
    float m  = s1 / cnt;
    float var = s2 / cnt - m * m;
    float A = gamma[lane] * rsqrtf(var + 1e-5f);
    sA[lane] = A;
    sB[lane] = beta[lane] - A * m;
  }
  __syncthreads();
  for (int j = 0; j < 16; ++j) {
    int nl = w * 16 + j;
    size_t off = ((size_t)b * NN + n0 + nl) * OO + lane;
    float A = sA[lane];
    float c0 = A * v[off] + sB[lane];
    float z = c0 + A * ((A > 0.f) ? umax[off] : umin[off]);
    zt[nl][lane] = fmaxf(z, 0.f);
  }
  __syncthreads();
  for (int j = 0; j < 16; ++j) {
    int o = w * 16 + j;
    out[((size_t)b * OO + o) * NN + n0 + lane] = zt[lane][o];
  }
}

// ---------------------------------------------------------------------------
extern "C" void kernel_launch(void* const* d_in, const int* in_sizes, int n_in,
                              void* d_out, int out_size, void* d_ws, size_t ws_size,
                              hipStream_t stream) {
  const float* x     = (const float*)d_in[0];
  const float* W     = (const float*)d_in[1];
  const float* bias  = (const float*)d_in[2];
  const float* gamma = (const float*)d_in[3];
  const float* beta  = (const float*)d_in[4];
  float* out = (float*)d_out;

  float* xt  = (float*)d_ws;                    // 2,097,152 f
  float* sq  = xt  + (size_t)BB*NN*CC;          //    32,768 f
  float* u   = sq  + (size_t)BB*NN;             // 2,097,152 f
  float* v   = u   + (size_t)BB*NN*OO;          // 2,097,152 f
  float* umx = v   + (size_t)BB*NN*OO;          // 2,097,152 f
  float* umn = umx + (size_t)BB*NN*OO;          // 2,097,152 f
  float* gS  = umn + (size_t)BB*NN*OO;          //     1,024 f (8 replicas)
  unsigned short* xb = (unsigned short*)(gS + 1024);          // 2,097,152 bf16
  unsigned* kcand = (unsigned*)(xb + (size_t)BB*NN*CC);       // 4,194,304 u32 (16 MB, 4 lists)

  hipMemsetAsync(gS, 0, 1024 * sizeof(float), stream);
  kprep<<<dim3(NN/64, BB), 256, 0, stream>>>(x, W, bias, xt, xb, sq, u, v);
  kknn8<<<dim3(2048),      256, 0, stream>>>(xb, sq, kcand);
  kpost<<<dim3(2048),      256, 0, stream>>>(kcand, xt, sq, u, v, umx, umn, gS);
  kout <<<dim3(NN/64, BB), 256, 0, stream>>>(v, umx, umn, gS, gamma, beta, out);
}

// Round 4
// 501.363 us; speedup vs baseline: 1.0524x; 1.0524x over previous
//
#include <hip/hip_runtime.h>
#include <hip/hip_bf16.h>

#define BB 8
#define CC 64
#define NN 4096
#define KK 20
#define OO 64
#define FMAXV 3.402823466e38f

typedef __attribute__((ext_vector_type(8))) short short8;   // 8 bf16 = 4 VGPRs (MFMA A/B frag)
typedef __attribute__((ext_vector_type(4))) float f32x4;    // MFMA C/D frag

// ---------------------------------------------------------------------------
// Kernel PREP (verified r7): transpose x (B,C,N)->xt/xb (B,N,C), sq, u/v GEMV.
// ---------------------------------------------------------------------------
__global__ __launch_bounds__(256) void kprep(const float* __restrict__ x,
                                             const float* __restrict__ W,
                                             const float* __restrict__ bias,
                                             float* __restrict__ xt,
                                             unsigned short* __restrict__ xb,
                                             float* __restrict__ sq,
                                             float* __restrict__ u,
                                             float* __restrict__ v) {
  __shared__ float tile[64][65];       // [c][n]
  const int b = blockIdx.y, n0 = blockIdx.x * 64;
  const int lane = threadIdx.x & 63, grp = threadIdx.x >> 6;
  #pragma unroll
  for (int j = 0; j < 16; ++j) {
    int c = grp + j * 4;
    tile[c][lane] = x[((size_t)b * CC + c) * NN + n0 + lane];
  }
  float w2r[64], wdr[64];
  const float4* W4 = (const float4*)W;
  #pragma unroll
  for (int c4 = 0; c4 < 16; ++c4) {
    float4 q1 = W4[lane * 32 + c4];       // W1 part
    float4 q2 = W4[lane * 32 + 16 + c4];  // W2 part
    w2r[c4*4]=q2.x; w2r[c4*4+1]=q2.y; w2r[c4*4+2]=q2.z; w2r[c4*4+3]=q2.w;
    wdr[c4*4]=q1.x-q2.x; wdr[c4*4+1]=q1.y-q2.y; wdr[c4*4+2]=q1.z-q2.z; wdr[c4*4+3]=q1.w-q2.w;
  }
  const float bo = bias[lane];
  __syncthreads();
  #pragma unroll
  for (int j = 0; j < 16; ++j) {
    int n = grp + j * 4;
    float vv = tile[lane][n];
    size_t off = ((size_t)b * NN + n0 + n) * CC + lane;
    xt[off] = vv;
    unsigned int uu = __builtin_bit_cast(unsigned int, vv);
    xb[off] = (unsigned short)((uu + 0x7FFFu + ((uu >> 16) & 1u)) >> 16);  // RNE bf16
  }
  if (threadIdx.x < 64) {
    float s = 0.f;
    #pragma unroll
    for (int c = 0; c < 64; ++c) { float vv = tile[c][lane]; s += vv * vv; }
    sq[(size_t)b * NN + n0 + lane] = s;
  }
  for (int j = 0; j < 16; ++j) {
    int nl = grp * 16 + j;
    float du = 0.f, dv = 0.f;
    #pragma unroll
    for (int c = 0; c < 64; ++c) {
      float xv = tile[c][nl];             // broadcast read
      du += w2r[c] * xv;
      dv += wdr[c] * xv;
    }
    size_t off = ((size_t)b * NN + n0 + nl) * OO + lane;
    u[off] = du;
    v[off] = dv + bo;
  }
}

// ---------------------------------------------------------------------------
// helpers (verified rounds 3-8)
// ---------------------------------------------------------------------------
__device__ __forceinline__ int lanes_below(unsigned long long m) {
  unsigned lo = (unsigned)m, hi = (unsigned)(m >> 32);
  int c = __builtin_amdgcn_mbcnt_lo(lo, 0);
  return (int)__builtin_amdgcn_mbcnt_hi(hi, (unsigned)c);
}

// monotone float->uint, truncate to 20 bits, pack 12-bit global col idx
__device__ __forceinline__ unsigned packkey(float d, int m) {
  unsigned u = __builtin_bit_cast(unsigned, d);
  u ^= ((int)u < 0) ? 0xFFFFFFFFu : 0x80000000u;
  return (u & 0xFFFFF000u) | (unsigned)m;
}

// loose inverse: float threshold >= every d whose packkey < t (superset filter)
__device__ __forceinline__ float unpackkey(unsigned t) {
  unsigned u = t | 0xFFFu;
  u = (u & 0x80000000u) ? (u ^ 0x80000000u) : ~u;
  return __builtin_bit_cast(float, u);
}

// full 64-element bitonic sort (ascending), 1 element per lane, 21 stages
__device__ __forceinline__ unsigned bitonic64(unsigned v, int lane) {
  #pragma unroll
  for (int k = 2; k <= 64; k <<= 1) {
    #pragma unroll
    for (int j = k >> 1; j >= 1; j >>= 1) {
      unsigned o = (unsigned)__shfl_xor((int)v, j);
      bool up    = ((lane & k) == 0);
      bool lower = ((lane & j) == 0);
      unsigned mn = (v < o) ? v : o;
      unsigned mx = (v < o) ? o : v;
      v = (up == lower) ? mn : mx;
    }
  }
  return v;
}

// bitonic MERGE (6 stages): input ascending in lanes 0-31, descending in 32-63
// -> output fully sorted ascending across 64 lanes.
__device__ __forceinline__ unsigned merge6(unsigned v, int lane) {
  #pragma unroll
  for (int j = 32; j >= 1; j >>= 1) {
    unsigned o = (unsigned)__shfl_xor((int)v, j);
    unsigned mn = (v < o) ? v : o;
    unsigned mx = (v < o) ? o : v;
    v = ((lane & j) == 0) ? mn : mx;
  }
  return v;
}

// ---------------------------------------------------------------------------
// Kernel KNN9 (r10): r9 quarter-split geometry, launch bound relaxed to
// (256,4). r9's (256,8) capped the allocator at 64 VGPR -> B-frag spills to
// scratch (315 MB fetch / 362 MB write per dispatch, VGPR_Count 32). The
// geometry already fits 8 blocks/CU naturally: LDS = 20480 B = 160 KB/8 and
// unforced register usage ~52 <= 64 -> HW gives 32 waves/CU on its own.
// Each wave: 16 rows x 1024 cols (16 tiles). Ring 48, wrapped o4/w4/r4.
// Self-match included (strict exact min, dropped in kpost).
// Output: kcand[b][quarter][row][32] SORTED ascending packed keys.
// ---------------------------------------------------------------------------
__global__ __launch_bounds__(256, 4) void kknn9(const unsigned short* __restrict__ xb,
                                                const float* __restrict__ sq,
                                                unsigned* __restrict__ kcand) {
  __shared__ unsigned slist[4][16][32];   //  8 KB: per-wave per-row sorted top-32
  __shared__ unsigned sbuf[4][16][48];    // 12 KB: per-wave per-row ring (outstanding <= 47)
  const int lane = threadIdx.x & 63, w = threadIdx.x >> 6;
  const int wid = blockIdx.x * 4 + w;            // 0..8191
  const int b = wid >> 10;
  const int quarter = (wid >> 8) & 3;
  const int n0g = (wid & 255) * 16;              // global row base
  const int ch0 = quarter * (NN / 4);            // global col base
  const int l15 = lane & 15, q = lane >> 4;
  const unsigned long long qmask = 0xFFFFull << (q * 16);

  const unsigned short* xbB = xb + (size_t)b * NN * CC;
  const float* sqB = sq + (size_t)b * NN;

  // init slist sentinels (per wave)
  #pragma unroll
  for (int i = 0; i < 8; ++i) {
    int idx = i * 64 + lane;
    slist[w][idx >> 5][idx & 31] = 0xFFFFFFFFu;
  }

  // A frags: rows n0g + l15, k = ks*32 + q*8
  short8 afr[2];
  #pragma unroll
  for (int ks = 0; ks < 2; ++ks)
    afr[ks] = __builtin_bit_cast(short8, *(const int4*)(xbB + (size_t)(n0g + l15) * CC + ks * 32 + q * 8));

  // per-lane state: slot j tracks row q*4+j
  float tauf4[4];
  int o4[4], w4[4], r4[4];                // outstanding, wrapped write ptr, wrapped read ptr
  #pragma unroll
  for (int j = 0; j < 4; ++j) { tauf4[j] = FMAXV; o4[j] = 0; w4[j] = 0; r4[j] = 0; }

  for (int t = 0; t < 16; ++t) {
    const int cb = ch0 + t * 64;
    short8 bfr[4][2];
    float sv[4];
    #pragma unroll
    for (int ct = 0; ct < 4; ++ct) {
      #pragma unroll
      for (int ks = 0; ks < 2; ++ks)
        bfr[ct][ks] = __builtin_bit_cast(short8,
            *(const int4*)(xbB + (size_t)(cb + ct * 16 + l15) * CC + ks * 32 + q * 8));
      sv[ct] = sqB[cb + ct * 16 + l15];
    }
    f32x4 acc[4];
    #pragma unroll
    for (int ct = 0; ct < 4; ++ct) {
      acc[ct] = (f32x4){0.f, 0.f, 0.f, 0.f};
      acc[ct] = __builtin_amdgcn_mfma_f32_16x16x32_bf16(afr[0], bfr[ct][0], acc[ct], 0, 0, 0);
      acc[ct] = __builtin_amdgcn_mfma_f32_16x16x32_bf16(afr[1], bfr[ct][1], acc[ct], 0, 0, 0);
    }

    #pragma unroll
    for (int j = 0; j < 4; ++j) {
      float dj[4];
      bool  pj[4];
      #pragma unroll
      for (int ct = 0; ct < 4; ++ct) {
        dj[ct] = sv[ct] - 2.f * acc[ct][j];
        pj[ct] = dj[ct] <= tauf4[j];
      }
      unsigned long long bl0 = __ballot(pj[0]);
      unsigned long long bl1 = __ballot(pj[1]);
      unsigned long long bl2 = __ballot(pj[2]);
      unsigned long long bl3 = __ballot(pj[3]);
      if (!(bl0 | bl1 | bl2 | bl3)) continue;

      const int rowl = q * 4 + j;
      #pragma unroll
      for (int ct = 0; ct < 4; ++ct) {
        unsigned long long blc = (ct == 0) ? bl0 : (ct == 1) ? bl1 : (ct == 2) ? bl2 : bl3;
        unsigned long long bq = blc & qmask;
        int pos = lanes_below(bq);
        int qc  = __popcll(bq);
        if (pj[ct]) {
          int idx = w4[j] + pos; if (idx >= 48) idx -= 48;
          sbuf[w][rowl][idx] = packkey(dj[ct], cb + ct * 16 + l15);
        }
        w4[j] += qc; if (w4[j] >= 48) w4[j] -= 48;
        o4[j] += qc;

        // merge-check per ct: outstanding <= 31+16 = 47 fits ring 48;
        // one merge restores the <=31 invariant.
        unsigned long long mb = __ballot(o4[j] >= 32);
        while (mb) {
          int src = __ffsll(mb) - 1;
          int qm = src >> 4;
          int rowm = qm * 4 + j;
          int rsrc = __shfl(r4[j], src);
          int ridx = rsrc + (lane - 32); if (ridx >= 48) ridx -= 48;
          unsigned v = (lane < 32) ? slist[w][rowm][lane]
                                   : sbuf[w][rowm][ridx];
          v = bitonic64(v, lane);
          if (lane < 32) slist[w][rowm][lane] = v;
          unsigned tn = (unsigned)__shfl((int)v, 31);
          if (q == qm) {
            tauf4[j] = unpackkey(tn);
            r4[j] += 32; if (r4[j] >= 48) r4[j] -= 48;
            o4[j] -= 32;
          }
          mb &= ~(0xFFFFull << (qm * 16));
        }
      }
    }
  }

  // flush leftovers (< 32 outstanding per row)
  #pragma unroll
  for (int j = 0; j < 4; ++j) {
    unsigned long long mb = __ballot(o4[j] > 0);
    while (mb) {
      int src = __ffsll(mb) - 1;
      int qm = src >> 4;
      int rowm = qm * 4 + j;
      int rsrc = __shfl(r4[j], src);
      int rem  = __shfl(o4[j], src);
      int ridx = rsrc + (lane - 32); if (ridx >= 48) ridx -= 48;
      unsigned v = (lane < 32) ? slist[w][rowm][lane]
                 : ((lane - 32) < rem ? sbuf[w][rowm][ridx] : 0xFFFFFFFFu);
      v = bitonic64(v, lane);
      if (lane < 32) slist[w][rowm][lane] = v;
      if (q == qm) o4[j] = 0;
      mb &= ~(0xFFFFull << (qm * 16));
    }
  }

  // write out sorted top-32 per row (coalesced)
  unsigned* kc = kcand + (((size_t)b * 4 + quarter) * NN + n0g) * 32;
  #pragma unroll
  for (int i = 0; i < 8; ++i) {
    int idx = i * 64 + lane;
    kc[idx] = slist[w][idx >> 5][idx & 31];
  }
}

// ---------------------------------------------------------------------------
// preselect (r9): union 4 SORTED quarter top-32 lists of one row via three
// 6-stage bitonic merges -> approx-top-32 in lanes 0-31 (ascending).
// ---------------------------------------------------------------------------
__device__ __forceinline__ unsigned preselect(const unsigned* __restrict__ kcB,
                                              int row, int lane) {
  const int li = (lane < 32) ? lane : (63 - lane);   // upper lanes load reversed
  unsigned v01 = (lane < 32) ? kcB[((size_t)0 * NN + row) * 32 + li]
                             : kcB[((size_t)1 * NN + row) * 32 + li];
  v01 = merge6(v01, lane);                           // sorted 64; low32 = A∪B top-32
  unsigned v23 = (lane < 32) ? kcB[((size_t)2 * NN + row) * 32 + li]
                             : kcB[((size_t)3 * NN + row) * 32 + li];
  v23 = merge6(v23, lane);                           // sorted 64; low32 = C∪D top-32
  unsigned sw = (unsigned)__shfl_xor((int)v23, 63);  // reverse into upper lanes
  unsigned vm = (lane < 32) ? v01 : sw;              // asc low / desc high = bitonic
  vm = merge6(vm, lane);                             // sorted 64; low32 = row top-32
  return vm;
}

// ---------------------------------------------------------------------------
// Kernel POST (r9): per row-pair, preselect approx-top-32 from the 4 quarter
// lists -> exact f32 refine (xt) -> sorted; rank 0 is ALWAYS self (exact
// strict min), neighbors are ranks 1..20. Gather u for stats into replicated
// gS; umax/umin.
// ---------------------------------------------------------------------------
__global__ __launch_bounds__(256) void kpost(const unsigned* __restrict__ kcand,
                                             const float* __restrict__ xt,
                                             const float* __restrict__ sq,
                                             const float* __restrict__ u,
                                             const float* __restrict__ v,
                                             float* __restrict__ umax,
                                             float* __restrict__ umin,
                                             float* __restrict__ gS) {
  const int lane = threadIdx.x & 63, w = threadIdx.x >> 6;
  const int gw = blockIdx.x * 4 + w;
  const int hl = lane & 31;
  float s1 = 0.f, s2 = 0.f;

  for (int it = 0; it < 2; ++it) {
    const int rbase = gw * 4 + it * 2;          // global row index (b*N+n), even
    const int b = rbase >> 12;
    const int n = rbase & (NN - 1);

    const unsigned* kcB = kcand + (size_t)b * 4 * NN * 32;
    unsigned keyN  = preselect(kcB, n,     lane);   // lanes 0-31: row n top-32
    unsigned keyN1 = preselect(kcB, n + 1, lane);   // lanes 0-31: row n+1 top-32
    unsigned kx = (unsigned)__shfl_xor((int)keyN1, 32);
    unsigned key = (lane < 32) ? keyN : kx;     // lanes 0-31: row n; 32-63: row n+1
    int m = (int)(key & 0xFFFu);
    const int rowg = n + ((lane >= 32) ? 1 : 0);

    // exact f32 key
    const float* xtB = xt + (size_t)b * NN * CC;
    const float* sqB = sq + (size_t)b * NN;
    const float4* pr = (const float4*)(xtB + (size_t)rowg * CC);
    const float4* pm = (const float4*)(xtB + (size_t)m * CC);
    float t0 = 0.f, t1 = 0.f, t2 = 0.f, t3 = 0.f;
    #pragma unroll
    for (int i = 0; i < 16; ++i) {
      float4 a = pr[i], c = pm[i];
      t0 += a.x * c.x; t1 += a.y * c.y; t2 += a.z * c.z; t3 += a.w * c.w;
    }
    float ev = sqB[m] - 2.f * ((t0 + t1) + (t2 + t3));

    // bitonic sort 32 (ev, m) pairs ascending within each 32-lane half
    #pragma unroll
    for (int k = 2; k <= 32; k <<= 1) {
      #pragma unroll
      for (int jj = k >> 1; jj >= 1; jj >>= 1) {
        float e2 = __shfl_xor(ev, jj);
        int   m2 = __shfl_xor(m, jj);
        bool up    = ((hl & k) == 0);
        bool lower = ((hl & jj) == 0);
        bool less  = (e2 < ev) || (e2 == ev && m2 < m);
        bool take  = (up == lower) ? less : !less;
        if (take) { ev = e2; m = m2; }
      }
    }

    // stats gather: lane = channel; rows n, n+1. Rank 0 is self -> skip it.
    const float* uB = u + (size_t)b * NN * OO;
    #pragma unroll
    for (int rr = 0; rr < 2; ++rr) {
      const int rown = n + rr;
      float vv = v[((size_t)b * NN + rown) * OO + lane];
      float mx = -FMAXV, mn = FMAXV;
      #pragma unroll
      for (int k = 0; k < KK; ++k) {
        int id = __shfl(m, rr * 32 + 1 + k);
        float uu = uB[(size_t)id * OO + lane];
        float y = vv + uu;
        s1 += y; s2 += y * y;
        mx = fmaxf(mx, uu); mn = fminf(mn, uu);
      }
      umax[((size_t)b * NN + rown) * OO + lane] = mx;
      umin[((size_t)b * NN + rown) * OO + lane] = mn;
    }
  }

  __shared__ float r1[4][64], r2[4][64];
  r1[w][lane] = s1; r2[w][lane] = s2;
  __syncthreads();
  if (w == 0) {
    float a = r1[0][lane] + r1[1][lane] + r1[2][lane] + r1[3][lane];
    float c = r2[0][lane] + r2[1][lane] + r2[2][lane] + r2[3][lane];
    float* g = gS + (blockIdx.x & 7) * 128;     // 8 replicas vs atomic serialization
    atomicAdd(&g[lane], a);
    atomicAdd(&g[64 + lane], c);
  }
}

// ---------------------------------------------------------------------------
// Kernel O (verified r7): normalize, affine, relu, max over k, transposed store
// ---------------------------------------------------------------------------
__global__ __launch_bounds__(256) void kout(const float* __restrict__ v,
                                            const float* __restrict__ umax,
                                            const float* __restrict__ umin,
                                            const float* __restrict__ gS,
                                            const float* __restrict__ gamma,
                                            const float* __restrict__ beta,
                                            float* __restrict__ out) {
  __shared__ float sA[64], sB[64];
  __shared__ float zt[64][65];
  const int b = blockIdx.y, n0 = blockIdx.x * 64;
  const int lane = threadIdx.x & 63, w = threadIdx.x >> 6;
  if (threadIdx.x < 64) {
    float s1 = 0.f, s2 = 0.f;
    #pragma unroll
    for (int rsub = 0; rsub < 8; ++rsub) {
      s1 += gS[rsub * 128 + lane];
      s2 += gS[rsub * 128 + 64 + lane];
    }
    const float cnt = (float)BB * NN * KK;
    float m  = s1 / cnt;
    float var = s2 / cnt - m * m;
    float A = gamma[lane] * rsqrtf(var + 1e-5f);
    sA[lane] = A;
    sB[lane] = beta[lane] - A * m;
  }
  __syncthreads();
  for (int j = 0; j < 16; ++j) {
    int nl = w * 16 + j;
    size_t off = ((size_t)b * NN + n0 + nl) * OO + lane;
    float A = sA[lane];
    float c0 = A * v[off] + sB[lane];
    float z = c0 + A * ((A > 0.f) ? umax[off] : umin[off]);
    zt[nl][lane] = fmaxf(z, 0.f);
  }
  __syncthreads();
  for (int j = 0; j < 16; ++j) {
    int o = w * 16 + j;
    out[((size_t)b * OO + o) * NN + n0 + lane] = zt[lane][o];
  }
}

// ---------------------------------------------------------------------------
extern "C" void kernel_launch(void* const* d_in, const int* in_sizes, int n_in,
                              void* d_out, int out_size, void* d_ws, size_t ws_size,
                              hipStream_t stream) {
  const float* x     = (const float*)d_in[0];
  const float* W     = (const float*)d_in[1];
  const float* bias  = (const float*)d_in[2];
  const float* gamma = (const float*)d_in[3];
  const float* beta  = (const float*)d_in[4];
  float* out = (float*)d_out;

  float* xt  = (float*)d_ws;                    // 2,097,152 f
  float* sq  = xt  + (size_t)BB*NN*CC;          //    32,768 f
  float* u   = sq  + (size_t)BB*NN;             // 2,097,152 f
  float* v   = u   + (size_t)BB*NN*OO;          // 2,097,152 f
  float* umx = v   + (size_t)BB*NN*OO;          // 2,097,152 f
  float* umn = umx + (size_t)BB*NN*OO;          // 2,097,152 f
  float* gS  = umn + (size_t)BB*NN*OO;          //     1,024 f (8 replicas)
  unsigned short* xb = (unsigned short*)(gS + 1024);          // 2,097,152 bf16
  unsigned* kcand = (unsigned*)(xb + (size_t)BB*NN*CC);       // 4,194,304 u32 (16 MB, 4 lists)

  hipMemsetAsync(gS, 0, 1024 * sizeof(float), stream);
  kprep<<<dim3(NN/64, BB), 256, 0, stream>>>(x, W, bias, xt, xb, sq, u, v);
  kknn9<<<dim3(2048),      256, 0, stream>>>(xb, sq, kcand);
  kpost<<<dim3(2048),      256, 0, stream>>>(kcand, xt, sq, u, v, umx, umn, gS);
  kout <<<dim3(NN/64, BB), 256, 0, stream>>>(v, umx, umn, gS, gamma, beta, out);
}

// Round 6
// 374.027 us; speedup vs baseline: 1.4107x; 1.3404x over previous
//
#include <hip/hip_runtime.h>
#include <hip/hip_bf16.h>

#define BB 8
#define CC 64
#define NN 4096
#define KK 20
#define OO 64
#define FMAXV 3.402823466e38f

typedef __attribute__((ext_vector_type(8))) short short8;   // 8 bf16 = 4 VGPRs (MFMA A/B frag)
typedef __attribute__((ext_vector_type(4))) float f32x4;    // MFMA C/D frag

// ---------------------------------------------------------------------------
// Kernel PREP (verified r7): transpose x (B,C,N)->xt/xb (B,N,C), sq, u/v GEMV.
// ---------------------------------------------------------------------------
__global__ __launch_bounds__(256) void kprep(const float* __restrict__ x,
                                             const float* __restrict__ W,
                                             const float* __restrict__ bias,
                                             float* __restrict__ xt,
                                             unsigned short* __restrict__ xb,
                                             float* __restrict__ sq,
                                             float* __restrict__ u,
                                             float* __restrict__ v) {
  __shared__ float tile[64][65];       // [c][n]
  const int b = blockIdx.y, n0 = blockIdx.x * 64;
  const int lane = threadIdx.x & 63, grp = threadIdx.x >> 6;
  #pragma unroll
  for (int j = 0; j < 16; ++j) {
    int c = grp + j * 4;
    tile[c][lane] = x[((size_t)b * CC + c) * NN + n0 + lane];
  }
  float w2r[64], wdr[64];
  const float4* W4 = (const float4*)W;
  #pragma unroll
  for (int c4 = 0; c4 < 16; ++c4) {
    float4 q1 = W4[lane * 32 + c4];       // W1 part
    float4 q2 = W4[lane * 32 + 16 + c4];  // W2 part
    w2r[c4*4]=q2.x; w2r[c4*4+1]=q2.y; w2r[c4*4+2]=q2.z; w2r[c4*4+3]=q2.w;
    wdr[c4*4]=q1.x-q2.x; wdr[c4*4+1]=q1.y-q2.y; wdr[c4*4+2]=q1.z-q2.z; wdr[c4*4+3]=q1.w-q2.w;
  }
  const float bo = bias[lane];
  __syncthreads();
  #pragma unroll
  for (int j = 0; j < 16; ++j) {
    int n = grp + j * 4;
    float vv = tile[lane][n];
    size_t off = ((size_t)b * NN + n0 + n) * CC + lane;
    xt[off] = vv;
    unsigned int uu = __builtin_bit_cast(unsigned int, vv);
    xb[off] = (unsigned short)((uu + 0x7FFFu + ((uu >> 16) & 1u)) >> 16);  // RNE bf16
  }
  if (threadIdx.x < 64) {
    float s = 0.f;
    #pragma unroll
    for (int c = 0; c < 64; ++c) { float vv = tile[c][lane]; s += vv * vv; }
    sq[(size_t)b * NN + n0 + lane] = s;
  }
  for (int j = 0; j < 16; ++j) {
    int nl = grp * 16 + j;
    float du = 0.f, dv = 0.f;
    #pragma unroll
    for (int c = 0; c < 64; ++c) {
      float xv = tile[c][nl];             // broadcast read
      du += w2r[c] * xv;
      dv += wdr[c] * xv;
    }
    size_t off = ((size_t)b * NN + n0 + nl) * OO + lane;
    u[off] = du;
    v[off] = dv + bo;
  }
}

// ---------------------------------------------------------------------------
// helpers (verified rounds 3-8)
// ---------------------------------------------------------------------------
__device__ __forceinline__ int lanes_below(unsigned long long m) {
  unsigned lo = (unsigned)m, hi = (unsigned)(m >> 32);
  int c = __builtin_amdgcn_mbcnt_lo(lo, 0);
  return (int)__builtin_amdgcn_mbcnt_hi(hi, (unsigned)c);
}

// monotone float->uint, truncate to 20 bits, pack 12-bit global col idx
__device__ __forceinline__ unsigned packkey(float d, int m) {
  unsigned u = __builtin_bit_cast(unsigned, d);
  u ^= ((int)u < 0) ? 0xFFFFFFFFu : 0x80000000u;
  return (u & 0xFFFFF000u) | (unsigned)m;
}

// loose inverse: float threshold >= every d whose packkey < t (superset filter)
__device__ __forceinline__ float unpackkey(unsigned t) {
  unsigned u = t | 0xFFFu;
  u = (u & 0x80000000u) ? (u ^ 0x80000000u) : ~u;
  return __builtin_bit_cast(float, u);
}

// full 64-element bitonic sort (ascending), 1 element per lane, 21 stages
__device__ __forceinline__ unsigned bitonic64(unsigned v, int lane) {
  #pragma unroll
  for (int k = 2; k <= 64; k <<= 1) {
    #pragma unroll
    for (int j = k >> 1; j >= 1; j >>= 1) {
      unsigned o = (unsigned)__shfl_xor((int)v, j);
      bool up    = ((lane & k) == 0);
      bool lower = ((lane & j) == 0);
      unsigned mn = (v < o) ? v : o;
      unsigned mx = (v < o) ? o : v;
      v = (up == lower) ? mn : mx;
    }
  }
  return v;
}

// bitonic MERGE (6 stages): input ascending in lanes 0-31, descending in 32-63
// -> output fully sorted ascending across 64 lanes.
__device__ __forceinline__ unsigned merge6(unsigned v, int lane) {
  #pragma unroll
  for (int j = 32; j >= 1; j >>= 1) {
    unsigned o = (unsigned)__shfl_xor((int)v, j);
    unsigned mn = (v < o) ? v : o;
    unsigned mx = (v < o) ? o : v;
    v = ((lane & j) == 0) ? mn : mx;
  }
  return v;
}

// ---------------------------------------------------------------------------
// do_merges (r12 = r11 + shfl-UB fix): service all rows in mb. When >=2 rows
// pending, PAIRED merge: sort row A's batch in lanes 0-31 and row B's in
// lanes 32-63 simultaneously (15 shared stages), then two 6-stage merges.
// r11 BUG: the reversal __shfl was inside a divergent ternary arm -> HIP UB
// (reading an inactive lane is undefined). r12 hoists BOTH reversal shfls so
// all 64 lanes execute them at full exec (the verified kpost idiom), with
// mod-64-masked source indices, then selects.
// ---------------------------------------------------------------------------
__device__ __forceinline__ void do_merges(unsigned long long mb, int j, int lane, int q,
                                          unsigned (*sl)[32], unsigned (*rg)[128],
                                          float& tau, int& cnt, int& done) {
  const int hl = lane & 31;
  while (mb) {
    int srcA = __ffsll(mb) - 1;
    int qA = srcA >> 4;
    mb &= ~(0xFFFFull << (qA * 16));
    if (mb) {
      int srcB = __ffsll(mb) - 1;
      int qB = srcB >> 4;
      mb &= ~(0xFFFFull << (qB * 16));
      const int rA = qA * 4 + j, rB = qB * 4 + j;
      int dA = __shfl(done, srcA);
      int rmA = __shfl(cnt, srcA) - dA;
      int dB = __shfl(done, srcB);
      int rmB = __shfl(cnt, srcB) - dB;
      int tkA = (rmA < 32) ? rmA : 32;
      int tkB = (rmB < 32) ? rmB : 32;
      // phase 1: sort A's batch (lanes 0-31) and B's batch (lanes 32-63)
      unsigned vs;
      if (lane < 32) vs = (hl < tkA) ? rg[rA][(dA + hl) & 127] : 0xFFFFFFFFu;
      else           vs = (hl < tkB) ? rg[rB][(dB + hl) & 127] : 0xFFFFFFFFu;
      #pragma unroll
      for (int k = 2; k <= 32; k <<= 1) {
        #pragma unroll
        for (int jj = k >> 1; jj >= 1; jj >>= 1) {
          unsigned o = (unsigned)__shfl_xor((int)vs, jj);
          bool up    = ((hl & k) == 0);
          bool lower = ((hl & jj) == 0);
          unsigned mn = (vs < o) ? vs : o;
          unsigned mx = (vs < o) ? o : vs;
          vs = (up == lower) ? mn : mx;
        }
      }
      // hoisted reversals: ALL lanes execute both shfls (full exec), select after
      unsigned revA = (unsigned)__shfl((int)vs, (63 - lane) & 63);  // lanes>=32: A-batch desc
      unsigned revB = (unsigned)__shfl((int)vs, (95 - lane) & 63);  // lanes>=32: B-batch desc
      // phase 2: merge A (slist asc in lanes 0-31, batch desc in 32-63)
      unsigned slA = (lane < 32) ? sl[rA][lane] : 0u;
      unsigned va = (lane < 32) ? slA : revA;
      va = merge6(va, lane);
      if (lane < 32) sl[rA][lane] = va;
      unsigned tnA = (unsigned)__shfl((int)va, 31);
      // phase 3: merge B
      unsigned slB = (lane < 32) ? sl[rB][lane] : 0u;
      unsigned vb = (lane < 32) ? slB : revB;
      vb = merge6(vb, lane);
      if (lane < 32) sl[rB][lane] = vb;
      unsigned tnB = (unsigned)__shfl((int)vb, 31);
      if (q == qA) { tau = unpackkey(tnA); done += tkA; }
      if (q == qB) { tau = unpackkey(tnB); done += tkB; }
    } else {
      const int rM = qA * 4 + j;
      int dM = __shfl(done, srcA);
      int rm = __shfl(cnt, srcA) - dM;
      int tk = (rm < 32) ? rm : 32;
      unsigned v = (lane < 32) ? sl[rM][lane]
                 : ((lane - 32) < tk ? rg[rM][(dM + lane - 32) & 127] : 0xFFFFFFFFu);
      v = bitonic64(v, lane);
      if (lane < 32) sl[rM][lane] = v;
      unsigned tn = (unsigned)__shfl((int)v, 31);
      if (q == qA) { tau = unpackkey(tn); done += tk; }
    }
  }
}

// ---------------------------------------------------------------------------
// Kernel KNN12 (r12): r8 half-split geometry + t0 direct-sort init + paired
// merges (shfl-UB fixed). Each wave: 16 rows x 2048 cols (half). Ring 128,
// fused 4-ct push, one merge-check per j-slot (outstanding <= 31+64 = 95).
// t0: tau=inf -> all 64 candidates/row pass -> unconditional ring write +
// one bitonic64 per row initializes slist AND tau (top-32-of-64 exact).
// Self-match included (strict exact min, dropped in kpost).
// Output: kcand[b][half][row][32] sorted packed keys.
// ---------------------------------------------------------------------------
__global__ __launch_bounds__(256, 4) void kknn12(const unsigned short* __restrict__ xb,
                                                 const float* __restrict__ sq,
                                                 unsigned* __restrict__ kcand) {
  __shared__ unsigned slist[4][16][32];   //  8 KB: per-wave per-row sorted top-32
  __shared__ unsigned sbuf[4][16][128];   // 32 KB: per-wave per-row ring (outstanding <= 95)
  const int lane = threadIdx.x & 63, w = threadIdx.x >> 6;
  const int wid = blockIdx.x * 4 + w;            // 0..4095
  const int b = wid >> 9;
  const int half = (wid >> 8) & 1;
  const int n0g = (wid & 255) * 16;              // global row base
  const int ch0 = half * (NN / 2);               // global col base
  const int l15 = lane & 15, q = lane >> 4;
  const unsigned long long qmask = 0xFFFFull << (q * 16);

  const unsigned short* xbB = xb + (size_t)b * NN * CC;
  const float* sqB = sq + (size_t)b * NN;

  // A frags: rows n0g + l15, k = ks*32 + q*8
  short8 afr[2];
  #pragma unroll
  for (int ks = 0; ks < 2; ++ks)
    afr[ks] = __builtin_bit_cast(short8, *(const int4*)(xbB + (size_t)(n0g + l15) * CC + ks * 32 + q * 8));

  // per-lane state: slot j tracks row q*4+j
  float tauf4[4];
  int cnt4[4], done4[4];
  #pragma unroll
  for (int j = 0; j < 4; ++j) { tauf4[j] = FMAXV; cnt4[j] = 0; done4[j] = 0; }

  // ---- t = 0: tau = inf, all 64 candidates per row pass -> direct sort init
  {
    const int cb = ch0;
    short8 bfr[4][2];
    float sv[4];
    #pragma unroll
    for (int ct = 0; ct < 4; ++ct) {
      #pragma unroll
      for (int ks = 0; ks < 2; ++ks)
        bfr[ct][ks] = __builtin_bit_cast(short8,
            *(const int4*)(xbB + (size_t)(cb + ct * 16 + l15) * CC + ks * 32 + q * 8));
      sv[ct] = sqB[cb + ct * 16 + l15];
    }
    f32x4 acc[4];
    #pragma unroll
    for (int ct = 0; ct < 4; ++ct) {
      acc[ct] = (f32x4){0.f, 0.f, 0.f, 0.f};
      acc[ct] = __builtin_amdgcn_mfma_f32_16x16x32_bf16(afr[0], bfr[ct][0], acc[ct], 0, 0, 0);
      acc[ct] = __builtin_amdgcn_mfma_f32_16x16x32_bf16(afr[1], bfr[ct][1], acc[ct], 0, 0, 0);
    }
    #pragma unroll
    for (int j = 0; j < 4; ++j) {
      const int rowl = q * 4 + j;
      #pragma unroll
      for (int ct = 0; ct < 4; ++ct)
        sbuf[w][rowl][ct * 16 + l15] = packkey(sv[ct] - 2.f * acc[ct][j], cb + ct * 16 + l15);
    }
    #pragma unroll
    for (int rowm = 0; rowm < 16; ++rowm) {
      unsigned v = sbuf[w][rowm][lane];
      v = bitonic64(v, lane);
      if (lane < 32) slist[w][rowm][lane] = v;
      unsigned tn = (unsigned)__shfl((int)v, 31);
      if (q == (rowm >> 2)) tauf4[rowm & 3] = unpackkey(tn);
    }
  }

  for (int t = 1; t < 32; ++t) {
    const int cb = ch0 + t * 64;
    short8 bfr[4][2];
    float sv[4];
    #pragma unroll
    for (int ct = 0; ct < 4; ++ct) {
      #pragma unroll
      for (int ks = 0; ks < 2; ++ks)
        bfr[ct][ks] = __builtin_bit_cast(short8,
            *(const int4*)(xbB + (size_t)(cb + ct * 16 + l15) * CC + ks * 32 + q * 8));
      sv[ct] = sqB[cb + ct * 16 + l15];
    }
    f32x4 acc[4];
    #pragma unroll
    for (int ct = 0; ct < 4; ++ct) {
      acc[ct] = (f32x4){0.f, 0.f, 0.f, 0.f};
      acc[ct] = __builtin_amdgcn_mfma_f32_16x16x32_bf16(afr[0], bfr[ct][0], acc[ct], 0, 0, 0);
      acc[ct] = __builtin_amdgcn_mfma_f32_16x16x32_bf16(afr[1], bfr[ct][1], acc[ct], 0, 0, 0);
    }

    #pragma unroll
    for (int j = 0; j < 4; ++j) {
      // distances for this row across all 4 col sub-tiles (self NOT excluded)
      float dv[4];
      bool  pj[4];
      #pragma unroll
      for (int ct = 0; ct < 4; ++ct) {
        dv[ct] = sv[ct] - 2.f * acc[ct][j];
        pj[ct] = dv[ct] <= tauf4[j];
      }
      unsigned long long b0 = __ballot(pj[0]);
      unsigned long long b1 = __ballot(pj[1]);
      unsigned long long b2 = __ballot(pj[2]);
      unsigned long long b3 = __ballot(pj[3]);
      if (!(b0 | b1 | b2 | b3)) continue;

      const int rowl = q * 4 + j;
      int base = cnt4[j];
      {
        unsigned long long bq = b0 & qmask;
        if (pj[0]) sbuf[w][rowl][(base + lanes_below(bq)) & 127] = packkey(dv[0], cb + 0 * 16 + l15);
        base += __popcll(bq);
      }
      {
        unsigned long long bq = b1 & qmask;
        if (pj[1]) sbuf[w][rowl][(base + lanes_below(bq)) & 127] = packkey(dv[1], cb + 1 * 16 + l15);
        base += __popcll(bq);
      }
      {
        unsigned long long bq = b2 & qmask;
        if (pj[2]) sbuf[w][rowl][(base + lanes_below(bq)) & 127] = packkey(dv[2], cb + 2 * 16 + l15);
        base += __popcll(bq);
      }
      {
        unsigned long long bq = b3 & qmask;
        if (pj[3]) sbuf[w][rowl][(base + lanes_below(bq)) & 127] = packkey(dv[3], cb + 3 * 16 + l15);
        base += __popcll(bq);
      }
      cnt4[j] = base;

      // merge-drain: a row may have up to 95 outstanding -> up to 2 passes
      for (;;) {
        unsigned long long mb = __ballot(cnt4[j] - done4[j] >= 32);
        if (!mb) break;
        do_merges(mb, j, lane, q, slist[w], sbuf[w], tauf4[j], cnt4[j], done4[j]);
      }
    }
  }

  // flush leftovers (<= 31 outstanding per row)
  #pragma unroll
  for (int j = 0; j < 4; ++j) {
    unsigned long long mb = __ballot(cnt4[j] > done4[j]);
    if (mb) do_merges(mb, j, lane, q, slist[w], sbuf[w], tauf4[j], cnt4[j], done4[j]);
  }

  // write out sorted top-32 per row (coalesced)
  unsigned* kc = kcand + (((size_t)b * 2 + half) * NN + n0g) * 32;
  #pragma unroll
  for (int i = 0; i < 8; ++i) {
    int idx = i * 64 + lane;
    kc[idx] = slist[w][idx >> 5][idx & 31];
  }
}

// ---------------------------------------------------------------------------
// Kernel POST (r8, verified): per row-pair, union the two half top-32 lists ->
// exact f32 refine (xt) -> sorted; rank 0 is ALWAYS self (exact strict min),
// neighbors are ranks 1..20. Gather u for stats into replicated gS; umax/umin.
// ---------------------------------------------------------------------------
__global__ __launch_bounds__(256) void kpost(const unsigned* __restrict__ kcand,
                                             const float* __restrict__ xt,
                                             const float* __restrict__ sq,
                                             const float* __restrict__ u,
                                             const float* __restrict__ v,
                                             float* __restrict__ umax,
                                             float* __restrict__ umin,
                                             float* __restrict__ gS) {
  const int lane = threadIdx.x & 63, w = threadIdx.x >> 6;
  const int gw = blockIdx.x * 4 + w;
  const int hl = lane & 31;
  float s1 = 0.f, s2 = 0.f;

  for (int it = 0; it < 2; ++it) {
    const int rbase = gw * 4 + it * 2;          // global row index (b*N+n), even
    const int b = rbase >> 12;
    const int n = rbase & (NN - 1);

    const unsigned* kc0 = kcand + (((size_t)b * 2 + 0) * NN) * 32;
    const unsigned* kc1 = kcand + (((size_t)b * 2 + 1) * NN) * 32;
    unsigned vA = (lane < 32) ? kc0[(size_t)n * 32 + lane] : kc1[(size_t)n * 32 + (lane - 32)];
    vA = bitonic64(vA, lane);
    unsigned vB = (lane < 32) ? kc0[(size_t)(n + 1) * 32 + lane] : kc1[(size_t)(n + 1) * 32 + (lane - 32)];
    vB = bitonic64(vB, lane);
    unsigned kx = (unsigned)__shfl_xor((int)vB, 32);
    unsigned key = (lane < 32) ? vA : kx;       // lanes 0-31: row n; 32-63: row n+1
    int m = (int)(key & 0xFFFu);
    const int rowg = n + ((lane >= 32) ? 1 : 0);

    // exact f32 key
    const float* xtB = xt + (size_t)b * NN * CC;
    const float* sqB = sq + (size_t)b * NN;
    const float4* pr = (const float4*)(xtB + (size_t)rowg * CC);
    const float4* pm = (const float4*)(xtB + (size_t)m * CC);
    float t0 = 0.f, t1 = 0.f, t2 = 0.f, t3 = 0.f;
    #pragma unroll
    for (int i = 0; i < 16; ++i) {
      float4 a = pr[i], c = pm[i];
      t0 += a.x * c.x; t1 += a.y * c.y; t2 += a.z * c.z; t3 += a.w * c.w;
    }
    float ev = sqB[m] - 2.f * ((t0 + t1) + (t2 + t3));

    // bitonic sort 32 (ev, m) pairs ascending within each 32-lane half
    #pragma unroll
    for (int k = 2; k <= 32; k <<= 1) {
      #pragma unroll
      for (int jj = k >> 1; jj >= 1; jj >>= 1) {
        float e2 = __shfl_xor(ev, jj);
        int   m2 = __shfl_xor(m, jj);
        bool up    = ((hl & k) == 0);
        bool lower = ((hl & jj) == 0);
        bool less  = (e2 < ev) || (e2 == ev && m2 < m);
        bool take  = (up == lower) ? less : !less;
        if (take) { ev = e2; m = m2; }
      }
    }

    // stats gather: lane = channel; rows n, n+1. Rank 0 is self -> skip it.
    const float* uB = u + (size_t)b * NN * OO;
    #pragma unroll
    for (int rr = 0; rr < 2; ++rr) {
      const int rown = n + rr;
      float vv = v[((size_t)b * NN + rown) * OO + lane];
      float mx = -FMAXV, mn = FMAXV;
      #pragma unroll
      for (int k = 0; k < KK; ++k) {
        int id = __shfl(m, rr * 32 + 1 + k);
        float uu = uB[(size_t)id * OO + lane];
        float y = vv + uu;
        s1 += y; s2 += y * y;
        mx = fmaxf(mx, uu); mn = fminf(mn, uu);
      }
      umax[((size_t)b * NN + rown) * OO + lane] = mx;
      umin[((size_t)b * NN + rown) * OO + lane] = mn;
    }
  }

  __shared__ float r1[4][64], r2[4][64];
  r1[w][lane] = s1; r2[w][lane] = s2;
  __syncthreads();
  if (w == 0) {
    float a = r1[0][lane] + r1[1][lane] + r1[2][lane] + r1[3][lane];
    float c = r2[0][lane] + r2[1][lane] + r2[2][lane] + r2[3][lane];
    float* g = gS + (blockIdx.x & 7) * 128;     // 8 replicas vs atomic serialization
    atomicAdd(&g[lane], a);
    atomicAdd(&g[64 + lane], c);
  }
}

// ---------------------------------------------------------------------------
// Kernel O (verified r7): normalize, affine, relu, max over k, transposed store
// ---------------------------------------------------------------------------
__global__ __launch_bounds__(256) void kout(const float* __restrict__ v,
                                            const float* __restrict__ umax,
                                            const float* __restrict__ umin,
                                            const float* __restrict__ gS,
                                            const float* __restrict__ gamma,
                                            const float* __restrict__ beta,
                                            float* __restrict__ out) {
  __shared__ float sA[64], sB[64];
  __shared__ float zt[64][65];
  const int b = blockIdx.y, n0 = blockIdx.x * 64;
  const int lane = threadIdx.x & 63, w = threadIdx.x >> 6;
  if (threadIdx.x < 64) {
    float s1 = 0.f, s2 = 0.f;
    #pragma unroll
    for (int rsub = 0; rsub < 8; ++rsub) {
      s1 += gS[rsub * 128 + lane];
      s2 += gS[rsub * 128 + 64 + lane];
    }
    const float cnt = (float)BB * NN * KK;
    float m  = s1 / cnt;
    float var = s2 / cnt - m * m;
    float A = gamma[lane] * rsqrtf(var + 1e-5f);
    sA[lane] = A;
    sB[lane] = beta[lane] - A * m;
  }
  __syncthreads();
  for (int j = 0; j < 16; ++j) {
    int nl = w * 16 + j;
    size_t off = ((size_t)b * NN + n0 + nl) * OO + lane;
    float A = sA[lane];
    float c0 = A * v[off] + sB[lane];
    float z = c0 + A * ((A > 0.f) ? umax[off] : umin[off]);
    zt[nl][lane] = fmaxf(z, 0.f);
  }
  __syncthreads();
  for (int j = 0; j < 16; ++j) {
    int o = w * 16 + j;
    out[((size_t)b * OO + o) * NN + n0 + lane] = zt[lane][o];
  }
}

// ---------------------------------------------------------------------------
extern "C" void kernel_launch(void* const* d_in, const int* in_sizes, int n_in,
                              void* d_out, int out_size, void* d_ws, size_t ws_size,
                              hipStream_t stream) {
  const float* x     = (const float*)d_in[0];
  const float* W     = (const float*)d_in[1];
  const float* bias  = (const float*)d_in[2];
  const float* gamma = (const float*)d_in[3];
  const float* beta  = (const float*)d_in[4];
  float* out = (float*)d_out;

  float* xt  = (float*)d_ws;                    // 2,097,152 f
  float* sq  = xt  + (size_t)BB*NN*CC;          //    32,768 f
  float* u   = sq  + (size_t)BB*NN;             // 2,097,152 f
  float* v   = u   + (size_t)BB*NN*OO;          // 2,097,152 f
  float* umx = v   + (size_t)BB*NN*OO;          // 2,097,152 f
  float* umn = umx + (size_t)BB*NN*OO;          // 2,097,152 f
  float* gS  = umn + (size_t)BB*NN*OO;          //     1,024 f (8 replicas)
  unsigned short* xb = (unsigned short*)(gS + 1024);          // 2,097,152 bf16
  unsigned* kcand = (unsigned*)(xb + (size_t)BB*NN*CC);       // 2,097,152 u32 (8 MB)

  hipMemsetAsync(gS, 0, 1024 * sizeof(float), stream);
  kprep<<<dim3(NN/64, BB), 256, 0, stream>>>(x, W, bias, xt, xb, sq, u, v);
  kknn12<<<dim3(1024),     256, 0, stream>>>(xb, sq, kcand);
  kpost<<<dim3(2048),      256, 0, stream>>>(kcand, xt, sq, u, v, umx, umn, gS);
  kout <<<dim3(NN/64, BB), 256, 0, stream>>>(v, umx, umn, gS, gamma, beta, out);
}

// Round 9
// 361.518 us; speedup vs baseline: 1.4595x; 1.0346x over previous
//
#include <hip/hip_runtime.h>
#include <hip/hip_bf16.h>

#define BB 8
#define CC 64
#define NN 4096
#define KK 20
#define OO 64
#define FMAXV 3.402823466e38f

typedef __attribute__((ext_vector_type(8))) short short8;   // 8 bf16 = 4 VGPRs (MFMA A/B frag)
typedef __attribute__((ext_vector_type(4))) float f32x4;    // MFMA C/D frag

// ---------------------------------------------------------------------------
// Kernel PREP (verified r7): transpose x (B,C,N)->xt/xb (B,N,C), sq, u/v GEMV.
// ---------------------------------------------------------------------------
__global__ __launch_bounds__(256) void kprep(const float* __restrict__ x,
                                             const float* __restrict__ W,
                                             const float* __restrict__ bias,
                                             float* __restrict__ xt,
                                             unsigned short* __restrict__ xb,
                                             float* __restrict__ sq,
                                             float* __restrict__ u,
                                             float* __restrict__ v) {
  __shared__ float tile[64][65];       // [c][n]
  const int b = blockIdx.y, n0 = blockIdx.x * 64;
  const int lane = threadIdx.x & 63, grp = threadIdx.x >> 6;
  #pragma unroll
  for (int j = 0; j < 16; ++j) {
    int c = grp + j * 4;
    tile[c][lane] = x[((size_t)b * CC + c) * NN + n0 + lane];
  }
  float w2r[64], wdr[64];
  const float4* W4 = (const float4*)W;
  #pragma unroll
  for (int c4 = 0; c4 < 16; ++c4) {
    float4 q1 = W4[lane * 32 + c4];       // W1 part
    float4 q2 = W4[lane * 32 + 16 + c4];  // W2 part
    w2r[c4*4]=q2.x; w2r[c4*4+1]=q2.y; w2r[c4*4+2]=q2.z; w2r[c4*4+3]=q2.w;
    wdr[c4*4]=q1.x-q2.x; wdr[c4*4+1]=q1.y-q2.y; wdr[c4*4+2]=q1.z-q2.z; wdr[c4*4+3]=q1.w-q2.w;
  }
  const float bo = bias[lane];
  __syncthreads();
  #pragma unroll
  for (int j = 0; j < 16; ++j) {
    int n = grp + j * 4;
    float vv = tile[lane][n];
    size_t off = ((size_t)b * NN + n0 + n) * CC + lane;
    xt[off] = vv;
    unsigned int uu = __builtin_bit_cast(unsigned int, vv);
    xb[off] = (unsigned short)((uu + 0x7FFFu + ((uu >> 16) & 1u)) >> 16);  // RNE bf16
  }
  if (threadIdx.x < 64) {
    float s = 0.f;
    #pragma unroll
    for (int c = 0; c < 64; ++c) { float vv = tile[c][lane]; s += vv * vv; }
    sq[(size_t)b * NN + n0 + lane] = s;
  }
  for (int j = 0; j < 16; ++j) {
    int nl = grp * 16 + j;
    float du = 0.f, dv = 0.f;
    #pragma unroll
    for (int c = 0; c < 64; ++c) {
      float xv = tile[c][nl];             // broadcast read
      du += w2r[c] * xv;
      dv += wdr[c] * xv;
    }
    size_t off = ((size_t)b * NN + n0 + nl) * OO + lane;
    u[off] = du;
    v[off] = dv + bo;
  }
}

// ---------------------------------------------------------------------------
// helpers (verified rounds 3-8)
// ---------------------------------------------------------------------------
__device__ __forceinline__ int lanes_below(unsigned long long m) {
  unsigned lo = (unsigned)m, hi = (unsigned)(m >> 32);
  int c = __builtin_amdgcn_mbcnt_lo(lo, 0);
  return (int)__builtin_amdgcn_mbcnt_hi(hi, (unsigned)c);
}

// monotone float->uint, truncate to 20 bits, pack 12-bit global col idx
__device__ __forceinline__ unsigned packkey(float d, int m) {
  unsigned u = __builtin_bit_cast(unsigned, d);
  u ^= ((int)u < 0) ? 0xFFFFFFFFu : 0x80000000u;
  return (u & 0xFFFFF000u) | (unsigned)m;
}

// loose inverse: float threshold >= every d whose packkey < t (superset filter)
__device__ __forceinline__ float unpackkey(unsigned t) {
  unsigned u = t | 0xFFFu;
  u = (u & 0x80000000u) ? (u ^ 0x80000000u) : ~u;
  return __builtin_bit_cast(float, u);
}

// ---------------------------------------------------------------------------
// r14: XOR lane-exchange. Masks < 32 use ds_swizzle BitMode (one DS op with
// immediate pattern, no bpermute address setup). Encodings verified against
// the ISA doc's butterfly examples: 0x041F/0x081F/0x101F/0x201F/0x401F for
// xor 1/2/4/8/16. Mask 32 falls back to __shfl_xor (verified r8-r12).
// DPP is intentionally NOT used (r13 failure suspect — parked).
// ---------------------------------------------------------------------------
template<int M>
__device__ __forceinline__ unsigned swz(unsigned v) {
  if constexpr (M < 32)
    return (unsigned)__builtin_amdgcn_ds_swizzle((int)v, (M << 10) | 0x1F);
  else
    return (unsigned)__shfl_xor((int)v, M);
}

// full 64-element bitonic sort (ascending), 1 element per lane. Network is
// byte-identical to the r12-verified loop form; only the shuffle instruction
// differs (swizzle for masks <32).
__device__ __forceinline__ unsigned bitonic64(unsigned v, int lane) {
#define BCE(J, K) { unsigned o_ = swz<J>(v);                                  \
    bool km_ = (((lane & (K)) == 0) == ((lane & (J)) == 0));                  \
    unsigned mn_ = (v < o_) ? v : o_, mx_ = (v < o_) ? o_ : v;                \
    v = km_ ? mn_ : mx_; }
  BCE(1, 2)
  BCE(2, 4)  BCE(1, 4)
  BCE(4, 8)  BCE(2, 8)  BCE(1, 8)
  BCE(8, 16) BCE(4, 16) BCE(2, 16) BCE(1, 16)
  BCE(16, 32) BCE(8, 32) BCE(4, 32) BCE(2, 32) BCE(1, 32)
  BCE(32, 64) BCE(16, 64) BCE(8, 64) BCE(4, 64) BCE(2, 64) BCE(1, 64)
#undef BCE
  return v;
}

// bitonic MERGE (6 stages): input ascending in lanes 0-31, descending in
// 32-63 -> sorted ascending. Same network as r12's merge6, swizzle stages.
__device__ __forceinline__ unsigned merge6(unsigned v, int lane) {
#define MCE(J) { unsigned o_ = swz<J>(v);                                     \
    unsigned mn_ = (v < o_) ? v : o_, mx_ = (v < o_) ? o_ : v;                \
    v = ((lane & (J)) == 0) ? mn_ : mx_; }
  MCE(32) MCE(16) MCE(8) MCE(4) MCE(2) MCE(1)
#undef MCE
  return v;
}

// ---------------------------------------------------------------------------
// do_merges (r14 = r12-verified structure, swizzle-substituted): service all
// rows in mb. Paired path: shared bitonic32 sort of two rows' batches, then
// reversal (hoisted full-exec __shfl, r12's UB-safe idiom) + two merge6.
// Single path: bitonic64 of slist|batch.
// ---------------------------------------------------------------------------
__device__ __forceinline__ void do_merges(unsigned long long mb, int j, int lane, int q,
                                          unsigned (*sl)[32], unsigned (*rg)[128],
                                          float& tau, int& cnt, int& done) {
  const int hl = lane & 31;
  while (mb) {
    int srcA = __ffsll(mb) - 1;
    int qA = srcA >> 4;
    mb &= ~(0xFFFFull << (qA * 16));
    if (mb) {
      int srcB = __ffsll(mb) - 1;
      int qB = srcB >> 4;
      mb &= ~(0xFFFFull << (qB * 16));
      const int rA = qA * 4 + j, rB = qB * 4 + j;
      int dA = __shfl(done, srcA);
      int rmA = __shfl(cnt, srcA) - dA;
      int dB = __shfl(done, srcB);
      int rmB = __shfl(cnt, srcB) - dB;
      int tkA = (rmA < 32) ? rmA : 32;
      int tkB = (rmB < 32) ? rmB : 32;
      // phase 1: sort A's batch (lanes 0-31) and B's batch (lanes 32-63)
      unsigned vs;
      if (lane < 32) vs = (hl < tkA) ? rg[rA][(dA + hl) & 127] : 0xFFFFFFFFu;
      else           vs = (hl < tkB) ? rg[rB][(dB + hl) & 127] : 0xFFFFFFFFu;
#define SCE(J, K) { unsigned o_ = swz<J>(vs);                                 \
    bool km_ = (((hl & (K)) == 0) == ((hl & (J)) == 0));                      \
    unsigned mn_ = (vs < o_) ? vs : o_, mx_ = (vs < o_) ? o_ : vs;            \
    vs = km_ ? mn_ : mx_; }
      SCE(1, 2)
      SCE(2, 4)  SCE(1, 4)
      SCE(4, 8)  SCE(2, 8)  SCE(1, 8)
      SCE(8, 16) SCE(4, 16) SCE(2, 16) SCE(1, 16)
      SCE(16, 32) SCE(8, 32) SCE(4, 32) SCE(2, 32) SCE(1, 32)
#undef SCE
      // hoisted reversals: ALL lanes execute both shfls (full exec), select after
      unsigned revA = (unsigned)__shfl((int)vs, (63 - lane) & 63);  // lanes>=32: A-batch desc
      unsigned revB = (unsigned)__shfl((int)vs, (95 - lane) & 63);  // lanes>=32: B-batch desc
      // phase 2: merge A (slist asc in lanes 0-31, batch desc in 32-63)
      unsigned slA = (lane < 32) ? sl[rA][lane] : 0u;
      unsigned va = (lane < 32) ? slA : revA;
      va = merge6(va, lane);
      if (lane < 32) sl[rA][lane] = va;
      unsigned tnA = (unsigned)__shfl((int)va, 31);
      // phase 3: merge B
      unsigned slB = (lane < 32) ? sl[rB][lane] : 0u;
      unsigned vb = (lane < 32) ? slB : revB;
      vb = merge6(vb, lane);
      if (lane < 32) sl[rB][lane] = vb;
      unsigned tnB = (unsigned)__shfl((int)vb, 31);
      if (q == qA) { tau = unpackkey(tnA); done += tkA; }
      if (q == qB) { tau = unpackkey(tnB); done += tkB; }
    } else {
      const int rM = qA * 4 + j;
      int dM = __shfl(done, srcA);
      int rm = __shfl(cnt, srcA) - dM;
      int tk = (rm < 32) ? rm : 32;
      unsigned v = (lane < 32) ? sl[rM][lane]
                 : ((lane - 32) < tk ? rg[rM][(dM + lane - 32) & 127] : 0xFFFFFFFFu);
      v = bitonic64(v, lane);
      if (lane < 32) sl[rM][lane] = v;
      unsigned tn = (unsigned)__shfl((int)v, 31);
      if (q == qA) { tau = unpackkey(tn); done += tk; }
    }
  }
}

// ---------------------------------------------------------------------------
// Kernel KNN14 (r14, resubmit after infra failure): r12-verified structure
// (half-split, t0 direct-sort init, fused 4-ct push, ring 128),
// swizzle-substituted sort cores.
// Output: kcand[b][half][row][32] sorted (ascending) packed keys.
// ---------------------------------------------------------------------------
__global__ __launch_bounds__(256, 4) void kknn14(const unsigned short* __restrict__ xb,
                                                 const float* __restrict__ sq,
                                                 unsigned* __restrict__ kcand) {
  __shared__ unsigned slist[4][16][32];   //  8 KB: per-wave per-row sorted top-32
  __shared__ unsigned sbuf[4][16][128];   // 32 KB: per-wave per-row ring (outstanding <= 95)
  const int lane = threadIdx.x & 63, w = threadIdx.x >> 6;
  const int wid = blockIdx.x * 4 + w;            // 0..4095
  const int b = wid >> 9;
  const int half = (wid >> 8) & 1;
  const int n0g = (wid & 255) * 16;              // global row base
  const int ch0 = half * (NN / 2);               // global col base
  const int l15 = lane & 15, q = lane >> 4;
  const unsigned long long qmask = 0xFFFFull << (q * 16);

  const unsigned short* xbB = xb + (size_t)b * NN * CC;
  const float* sqB = sq + (size_t)b * NN;

  // A frags: rows n0g + l15, k = ks*32 + q*8
  short8 afr[2];
  #pragma unroll
  for (int ks = 0; ks < 2; ++ks)
    afr[ks] = __builtin_bit_cast(short8, *(const int4*)(xbB + (size_t)(n0g + l15) * CC + ks * 32 + q * 8));

  // per-lane state: slot j tracks row q*4+j
  float tauf4[4];
  int cnt4[4], done4[4];
  #pragma unroll
  for (int j = 0; j < 4; ++j) { tauf4[j] = FMAXV; cnt4[j] = 0; done4[j] = 0; }

  // ---- t = 0: tau = inf, all 64 candidates per row pass -> direct sort init
  {
    const int cb = ch0;
    short8 bfr[4][2];
    float sv[4];
    #pragma unroll
    for (int ct = 0; ct < 4; ++ct) {
      #pragma unroll
      for (int ks = 0; ks < 2; ++ks)
        bfr[ct][ks] = __builtin_bit_cast(short8,
            *(const int4*)(xbB + (size_t)(cb + ct * 16 + l15) * CC + ks * 32 + q * 8));
      sv[ct] = sqB[cb + ct * 16 + l15];
    }
    f32x4 acc[4];
    #pragma unroll
    for (int ct = 0; ct < 4; ++ct) {
      acc[ct] = (f32x4){0.f, 0.f, 0.f, 0.f};
      acc[ct] = __builtin_amdgcn_mfma_f32_16x16x32_bf16(afr[0], bfr[ct][0], acc[ct], 0, 0, 0);
      acc[ct] = __builtin_amdgcn_mfma_f32_16x16x32_bf16(afr[1], bfr[ct][1], acc[ct], 0, 0, 0);
    }
    #pragma unroll
    for (int j = 0; j < 4; ++j) {
      const int rowl = q * 4 + j;
      #pragma unroll
      for (int ct = 0; ct < 4; ++ct)
        sbuf[w][rowl][ct * 16 + l15] = packkey(sv[ct] - 2.f * acc[ct][j], cb + ct * 16 + l15);
    }
    #pragma unroll
    for (int rowm = 0; rowm < 16; ++rowm) {
      unsigned v = sbuf[w][rowm][lane];
      v = bitonic64(v, lane);
      if (lane < 32) slist[w][rowm][lane] = v;
      unsigned tn = (unsigned)__shfl((int)v, 31);
      if (q == (rowm >> 2)) tauf4[rowm & 3] = unpackkey(tn);
    }
  }

  for (int t = 1; t < 32; ++t) {
    const int cb = ch0 + t * 64;
    short8 bfr[4][2];
    float sv[4];
    #pragma unroll
    for (int ct = 0; ct < 4; ++ct) {
      #pragma unroll
      for (int ks = 0; ks < 2; ++ks)
        bfr[ct][ks] = __builtin_bit_cast(short8,
            *(const int4*)(xbB + (size_t)(cb + ct * 16 + l15) * CC + ks * 32 + q * 8));
      sv[ct] = sqB[cb + ct * 16 + l15];
    }
    f32x4 acc[4];
    #pragma unroll
    for (int ct = 0; ct < 4; ++ct) {
      acc[ct] = (f32x4){0.f, 0.f, 0.f, 0.f};
      acc[ct] = __builtin_amdgcn_mfma_f32_16x16x32_bf16(afr[0], bfr[ct][0], acc[ct], 0, 0, 0);
      acc[ct] = __builtin_amdgcn_mfma_f32_16x16x32_bf16(afr[1], bfr[ct][1], acc[ct], 0, 0, 0);
    }

    #pragma unroll
    for (int j = 0; j < 4; ++j) {
      // distances for this row across all 4 col sub-tiles (self NOT excluded)
      float dv[4];
      bool  pj[4];
      #pragma unroll
      for (int ct = 0; ct < 4; ++ct) {
        dv[ct] = sv[ct] - 2.f * acc[ct][j];
        pj[ct] = dv[ct] <= tauf4[j];
      }
      unsigned long long b0 = __ballot(pj[0]);
      unsigned long long b1 = __ballot(pj[1]);
      unsigned long long b2 = __ballot(pj[2]);
      unsigned long long b3 = __ballot(pj[3]);
      if (!(b0 | b1 | b2 | b3)) continue;

      const int rowl = q * 4 + j;
      int base = cnt4[j];
      {
        unsigned long long bq = b0 & qmask;
        if (pj[0]) sbuf[w][rowl][(base + lanes_below(bq)) & 127] = packkey(dv[0], cb + 0 * 16 + l15);
        base += __popcll(bq);
      }
      {
        unsigned long long bq = b1 & qmask;
        if (pj[1]) sbuf[w][rowl][(base + lanes_below(bq)) & 127] = packkey(dv[1], cb + 1 * 16 + l15);
        base += __popcll(bq);
      }
      {
        unsigned long long bq = b2 & qmask;
        if (pj[2]) sbuf[w][rowl][(base + lanes_below(bq)) & 127] = packkey(dv[2], cb + 2 * 16 + l15);
        base += __popcll(bq);
      }
      {
        unsigned long long bq = b3 & qmask;
        if (pj[3]) sbuf[w][rowl][(base + lanes_below(bq)) & 127] = packkey(dv[3], cb + 3 * 16 + l15);
        base += __popcll(bq);
      }
      cnt4[j] = base;

      // merge-drain: a row may have up to 95 outstanding -> up to 2 passes
      for (;;) {
        unsigned long long mb = __ballot(cnt4[j] - done4[j] >= 32);
        if (!mb) break;
        do_merges(mb, j, lane, q, slist[w], sbuf[w], tauf4[j], cnt4[j], done4[j]);
      }
    }
  }

  // flush leftovers (<= 31 outstanding per row)
  #pragma unroll
  for (int j = 0; j < 4; ++j) {
    unsigned long long mb = __ballot(cnt4[j] > done4[j]);
    if (mb) do_merges(mb, j, lane, q, slist[w], sbuf[w], tauf4[j], cnt4[j], done4[j]);
  }

  // write out sorted top-32 per row (coalesced)
  unsigned* kc = kcand + (((size_t)b * 2 + half) * NN + n0g) * 32;
  #pragma unroll
  for (int i = 0; i < 8; ++i) {
    int idx = i * 64 + lane;
    kc[idx] = slist[w][idx >> 5][idx & 31];
  }
}

// ---------------------------------------------------------------------------
// Kernel POST (r14): union of the two ASCENDING half-lists via the r9-verified
// reversed-load + merge6 pattern (6 stages vs 21-stage full sort). Refine
// (ev,m) bitonic-32 network identical to r12, swizzle stages. Rank 0 is
// ALWAYS self (exact strict min); neighbors are ranks 1..20. Stats into
// replicated gS; umax/umin.
// ---------------------------------------------------------------------------
__global__ __launch_bounds__(256) void kpost(const unsigned* __restrict__ kcand,
                                             const float* __restrict__ xt,
                                             const float* __restrict__ sq,
                                             const float* __restrict__ u,
                                             const float* __restrict__ v,
                                             float* __restrict__ umax,
                                             float* __restrict__ umin,
                                             float* __restrict__ gS) {
  const int lane = threadIdx.x & 63, w = threadIdx.x >> 6;
  const int gw = blockIdx.x * 4 + w;
  const int hl = lane & 31;
  float s1 = 0.f, s2 = 0.f;

  for (int it = 0; it < 2; ++it) {
    const int rbase = gw * 4 + it * 2;          // global row index (b*N+n), even
    const int b = rbase >> 12;
    const int n = rbase & (NN - 1);

    const unsigned* kc0 = kcand + (((size_t)b * 2 + 0) * NN) * 32;
    const unsigned* kc1 = kcand + (((size_t)b * 2 + 1) * NN) * 32;
    // upper lanes load reversed -> asc lower | desc upper = bitonic -> merge6
    const int li = (lane < 32) ? lane : (63 - lane);
    unsigned vA = (lane < 32) ? kc0[(size_t)n * 32 + li] : kc1[(size_t)n * 32 + li];
    vA = merge6(vA, lane);
    unsigned vB = (lane < 32) ? kc0[(size_t)(n + 1) * 32 + li] : kc1[(size_t)(n + 1) * 32 + li];
    vB = merge6(vB, lane);
    unsigned kx = (unsigned)__shfl_xor((int)vB, 32);
    unsigned key = (lane < 32) ? vA : kx;       // lanes 0-31: row n; 32-63: row n+1
    int m = (int)(key & 0xFFFu);
    const int rowg = n + ((lane >= 32) ? 1 : 0);

    // exact f32 key
    const float* xtB = xt + (size_t)b * NN * CC;
    const float* sqB = sq + (size_t)b * NN;
    const float4* pr = (const float4*)(xtB + (size_t)rowg * CC);
    const float4* pm = (const float4*)(xtB + (size_t)m * CC);
    float t0 = 0.f, t1 = 0.f, t2 = 0.f, t3 = 0.f;
    #pragma unroll
    for (int i = 0; i < 16; ++i) {
      float4 a = pr[i], c = pm[i];
      t0 += a.x * c.x; t1 += a.y * c.y; t2 += a.z * c.z; t3 += a.w * c.w;
    }
    float ev = sqB[m] - 2.f * ((t0 + t1) + (t2 + t3));

    // bitonic sort of 32 (ev,m) pairs ascending within each 32-lane half
    // (network identical to r12's loop; swizzle stages)
#define PCE(J, K) {                                                            \
    float e2_ = __builtin_bit_cast(float, swz<J>(__builtin_bit_cast(unsigned, ev))); \
    int   m2_ = (int)swz<J>((unsigned)m);                                      \
    bool up_ = ((hl & (K)) == 0), lo_ = ((hl & (J)) == 0);                     \
    bool less_ = (e2_ < ev) || (e2_ == ev && m2_ < m);                         \
    bool take_ = (up_ == lo_) ? less_ : !less_;                                \
    if (take_) { ev = e2_; m = m2_; } }
    PCE(1, 2)
    PCE(2, 4)  PCE(1, 4)
    PCE(4, 8)  PCE(2, 8)  PCE(1, 8)
    PCE(8, 16) PCE(4, 16) PCE(2, 16) PCE(1, 16)
    PCE(16, 32) PCE(8, 32) PCE(4, 32) PCE(2, 32) PCE(1, 32)
#undef PCE

    // stats gather: lane = channel; rows n, n+1. Rank 0 is self -> skip it.
    const float* uB = u + (size_t)b * NN * OO;
    #pragma unroll
    for (int rr = 0; rr < 2; ++rr) {
      const int rown = n + rr;
      float vv = v[((size_t)b * NN + rown) * OO + lane];
      float mx = -FMAXV, mn = FMAXV;
      #pragma unroll
      for (int k = 0; k < KK; ++k) {
        int id = __shfl(m, rr * 32 + 1 + k);
        float uu = uB[(size_t)id * OO + lane];
        float y = vv + uu;
        s1 += y; s2 += y * y;
        mx = fmaxf(mx, uu); mn = fminf(mn, uu);
      }
      umax[((size_t)b * NN + rown) * OO + lane] = mx;
      umin[((size_t)b * NN + rown) * OO + lane] = mn;
    }
  }

  __shared__ float r1[4][64], r2[4][64];
  r1[w][lane] = s1; r2[w][lane] = s2;
  __syncthreads();
  if (w == 0) {
    float a = r1[0][lane] + r1[1][lane] + r1[2][lane] + r1[3][lane];
    float c = r2[0][lane] + r2[1][lane] + r2[2][lane] + r2[3][lane];
    float* g = gS + (blockIdx.x & 7) * 128;     // 8 replicas vs atomic serialization
    atomicAdd(&g[lane], a);
    atomicAdd(&g[64 + lane], c);
  }
}

// ---------------------------------------------------------------------------
// Kernel O (verified r7): normalize, affine, relu, max over k, transposed store
// ---------------------------------------------------------------------------
__global__ __launch_bounds__(256) void kout(const float* __restrict__ v,
                                            const float* __restrict__ umax,
                                            const float* __restrict__ umin,
                                            const float* __restrict__ gS,
                                            const float* __restrict__ gamma,
                                            const float* __restrict__ beta,
                                            float* __restrict__ out) {
  __shared__ float sA[64], sB[64];
  __shared__ float zt[64][65];
  const int b = blockIdx.y, n0 = blockIdx.x * 64;
  const int lane = threadIdx.x & 63, w = threadIdx.x >> 6;
  if (threadIdx.x < 64) {
    float s1 = 0.f, s2 = 0.f;
    #pragma unroll
    for (int rsub = 0; rsub < 8; ++rsub) {
      s1 += gS[rsub * 128 + lane];
      s2 += gS[rsub * 128 + 64 + lane];
    }
    const float cnt = (float)BB * NN * KK;
    float m  = s1 / cnt;
    float var = s2 / cnt - m * m;
    float A = gamma[lane] * rsqrtf(var + 1e-5f);
    sA[lane] = A;
    sB[lane] = beta[lane] - A * m;
  }
  __syncthreads();
  for (int j = 0; j < 16; ++j) {
    int nl = w * 16 + j;
    size_t off = ((size_t)b * NN + n0 + nl) * OO + lane;
    float A = sA[lane];
    float c0 = A * v[off] + sB[lane];
    float z = c0 + A * ((A > 0.f) ? umax[off] : umin[off]);
    zt[nl][lane] = fmaxf(z, 0.f);
  }
  __syncthreads();
  for (int j = 0; j < 16; ++j) {
    int o = w * 16 + j;
    out[((size_t)b * OO + o) * NN + n0 + lane] = zt[lane][o];
  }
}

// ---------------------------------------------------------------------------
extern "C" void kernel_launch(void* const* d_in, const int* in_sizes, int n_in,
                              void* d_out, int out_size, void* d_ws, size_t ws_size,
                              hipStream_t stream) {
  const float* x     = (const float*)d_in[0];
  const float* W     = (const float*)d_in[1];
  const float* bias  = (const float*)d_in[2];
  const float* gamma = (const float*)d_in[3];
  const float* beta  = (const float*)d_in[4];
  float* out = (float*)d_out;

  float* xt  = (float*)d_ws;                    // 2,097,152 f
  float* sq  = xt  + (size_t)BB*NN*CC;          //    32,768 f
  float* u   = sq  + (size_t)BB*NN;             // 2,097,152 f
  float* v   = u   + (size_t)BB*NN*OO;          // 2,097,152 f
  float* umx = v   + (size_t)BB*NN*OO;          // 2,097,152 f
  float* umn = umx + (size_t)BB*NN*OO;          // 2,097,152 f
  float* gS  = umn + (size_t)BB*NN*OO;          //     1,024 f (8 replicas)
  unsigned short* xb = (unsigned short*)(gS + 1024);          // 2,097,152 bf16
  unsigned* kcand = (unsigned*)(xb + (size_t)BB*NN*CC);       // 2,097,152 u32 (8 MB)

  hipMemsetAsync(gS, 0, 1024 * sizeof(float), stream);
  kprep<<<dim3(NN/64, BB), 256, 0, stream>>>(x, W, bias, xt, xb, sq, u, v);
  kknn14<<<dim3(1024),     256, 0, stream>>>(xb, sq, kcand);
  kpost<<<dim3(2048),      256, 0, stream>>>(kcand, xt, sq, u, v, umx, umn, gS);
  kout <<<dim3(NN/64, BB), 256, 0, stream>>>(v, umx, umn, gS, gamma, beta, out);
}